// Round 13
// baseline (24.994 us; speedup 1.0000x reference)
//
#include <hip/hip_runtime.h>
#include <math.h>

#define NCC  32
#define EPSF 1e-10f
#define TPB  512

// W (d_ws) layout in floats
#define WOFF_CAB 0      // float2 cAB[32]    {a,b}                  (64 f)
#define WOFF_TA  64     // float2 tA[64]     {vc, ln2/a_s}          (128 f)
#define WOFF_AF  192    // float4 aF[32]     {a, b/a_s, b, 0}       (128 f)
#define WOFF_SL  320    // float2 SL[64][33] {S_k, L_k}             (4224 f)
#define WOFF_MT  4544   // uchar mtab[64][128] packed               (2048 f)
#define WTOT     6592

// ---------------------------------------------------------------------------
// Compile-time reproduction of numpy's SVD null-space basis (validated R1/R4):
// np.linalg.svd -> dgesdd (m=31<n=64, jobz='A') -> Path 4t: Vt[31:,:] ==
// Q[31:,:] of the Householder LQ (dgelqf) of L. A = B@theta = Q^T [0;theta].
// ---------------------------------------------------------------------------
struct MTab { float mt[33][64]; };

constexpr double csqrt_(double x) {
    double y = x > 1.0 ? x : 1.0;
    for (int i = 0; i < 80; ++i) y = 0.5 * (y + x / y);
    return y;
}

constexpr MTab make_mtab() {
    double Lm[31][64] = {};
    for (int k = 1; k < 32; ++k) {
        double xk = (double)k / 32.0;
        Lm[k - 1][2 * (k - 1)]     = xk;
        Lm[k - 1][2 * (k - 1) + 1] = 1.0;
        Lm[k - 1][2 * k]           = -xk;
        Lm[k - 1][2 * k + 1]       = -1.0;
    }
    double tau[31] = {};
    for (int i = 0; i < 31; ++i) {
        int E = 2 * i + 3; if (E > 63) E = 63;
        double xn2 = 0.0;
        for (int p = i + 1; p <= E; ++p) xn2 += Lm[i][p] * Lm[i][p];
        const double alpha = Lm[i][i];
        double tu = 0.0, sc = 0.0;
        if (xn2 != 0.0) {
            const double nrm  = csqrt_(alpha * alpha + xn2);
            const double beta = (alpha >= 0.0) ? -nrm : nrm;   // dlarfg sign
            tu = (beta - alpha) / beta;
            sc = 1.0 / (alpha - beta);
        }
        for (int p = i + 1; p <= E; ++p) Lm[i][p] *= sc;
        Lm[i][i] = 1.0;
        tau[i] = tu;
        for (int j = i + 1; j < 31; ++j) {
            double s = 0.0;
            for (int p = i; p <= E; ++p) s += Lm[i][p] * Lm[j][p];
            s *= tu;
            for (int p = i; p <= E; ++p) Lm[j][p] -= s * Lm[i][p];
        }
    }
    MTab o{};
    for (int col = 0; col < 33; ++col) {
        double u[64] = {};
        u[31 + col] = 1.0;
        for (int i = 30; i >= 0; --i) {
            int E = 2 * i + 3; if (E > 63) E = 63;
            double s = 0.0;
            for (int p = i; p <= E; ++p) s += Lm[i][p] * u[p];
            s *= tau[i];
            for (int p = i; p <= E; ++p) u[p] -= s * Lm[i][p];
        }
        for (int p = 0; p < 64; ++p) o.mt[col][p] = (float)u[p];
    }
    return o;
}

__constant__ const MTab dM = make_mtab();

// ---------------------------------------------------------------------------
// Setup kernel (one block): builds all tables once. t_hit/cumsum use the
// reference's exact expressions (libm logf, IEEE divides, fadd chains).
// mtab[row][u] = #{k: S_k < u/128} — a lower bound on the crossing count,
// fixed up exactly in the main kernel by the defining predicate.
// ---------------------------------------------------------------------------
__global__ __launch_bounds__(TPB) void cpab_setup(const float* __restrict__ theta,
                                                  float* __restrict__ W) {
    __shared__ float  sA[64];
    __shared__ float  aS[NCC], bS[NCC], vLS[NCC], vRS[NCC], laS[NCC];
    __shared__ float  thf[2][NCC], ljf[2][NCC];
    __shared__ float2 SLs[64][33];
    const int   tid = threadIdx.x;
    const float INF = __builtin_inff();

    if (tid < 64) {
        float acc = 0.0f;
#pragma unroll
        for (int j = 0; j < 33; ++j) acc = fmaf(dM.mt[j][tid], theta[j], acc);
        sA[tid] = acc;
    }
    __syncthreads();
    if (tid < NCC) {
        const float a   = sA[2 * tid];
        const float b   = sA[2 * tid + 1];
        const bool  big = fabsf(a) > EPSF;
        const float vL  = __fadd_rn(__fmul_rn(a, __fmul_rn((float)tid,       0.03125f)), b);
        const float vR  = __fadd_rn(__fmul_rn(a, __fmul_rn((float)(tid + 1), 0.03125f)), b);
        const float boa = b / (big ? a : 1.0f);                 // IEEE divide
        aS[tid] = a; bS[tid] = b; vLS[tid] = vL; vRS[tid] = vR;
        laS[tid] = (float)(0.6931471805599453094 / (double)(big ? a : 1.0f));
        W[WOFF_CAB + 2 * tid]     = a;
        W[WOFF_CAB + 2 * tid + 1] = b;
        W[WOFF_AF + 4 * tid]     = a;
        W[WOFF_AF + 4 * tid + 1] = boa;
        W[WOFF_AF + 4 * tid + 2] = b;
        W[WOFF_AF + 4 * tid + 3] = 0.0f;
    }
    __syncthreads();
    if (tid < 2 * NCC) {
        // thf[dd][c]: reference-exact t_hit for motion dir dd at cell c
        // (dd=1: entry c*h, target vR; dd=0: entry (c+1)*h, target vL).
        const int   c     = tid & 31;
        const int   dd    = tid >> 5;
        const float a     = aS[c];
        const float b     = bS[c];
        const float entry = __fmul_rn((float)(c + (dd ? 0 : 1)), 0.03125f);
        const float v     = dd ? vLS[c] : vRS[c];
        const bool  dirA  = v > 0.0f;
        const bool  fin   = dirA ? (c < NCC - 1) : (c > 0);
        const float xb    = __fmul_rn((float)(c + (dirA ? 1 : 0)), 0.03125f);
        const float xcs   = fin ? xb : entry;
        const float vc    = fin ? (dirA ? vRS[c] : vLS[c]) : v;
        const bool  v0    = (v == 0.0f);
        const float r     = vc / (v0 ? 1.0f : v);               // IEEE divide
        const bool  big   = fabsf(a) > EPSF;
        const float a_s   = big ? a : 1.0f;
        const float th_a  = logf(fmaxf(r, EPSF)) / a_s;         // libm + divide
        const float bb    = (fabsf(b) > EPSF) ? b : 1.0f;
        const float th_b  = __fsub_rn(xcs, entry) / bb;
        float t_hit = big ? ((r > EPSF) ? th_a : INF) : th_b;
        const bool valid = fin && !v0 && (t_hit > 0.0f);
        t_hit = valid ? t_hit : INF;
        thf[dd][c] = t_hit;
        ljf[dd][c] = __fmul_rn(a, t_hit);
        // step-0 table for motion dir dd at cell c: {target vc, ln2/a_s}
        const int rowT = dd * 32 + c;
        W[WOFF_TA + 2 * rowT]     = dd ? vRS[c] : vLS[c];
        W[WOFF_TA + 2 * rowT + 1] = laS[c];
    }
    __syncthreads();
    if (tid < 2 * NCC) {
        // cumsum row (dd, c1): exact fadd chains; guards th=4 (> any t0)
        const int dd = tid >> 5, c1 = tid & 31, dh = dd ? 1 : -1;
        float S = 0.0f, LJ = 0.0f;
        SLs[tid][0] = make_float2(0.0f, 0.0f);
#pragma unroll
        for (int k = 1; k <= 32; ++k) {
            const int cell = c1 + (k - 1) * dh;
            float th = 4.0f, lp = 0.0f;
            if (cell >= 0 && cell < NCC) {
                th = thf[dd][cell];
                lp = ljf[dd][cell];
                if (!(th <= 2.0f)) { th = 4.0f; lp = 0.0f; }
            }
            S  = __fadd_rn(S, th);
            LJ = __fadd_rn(LJ, lp);
            SLs[tid][k] = make_float2(S, LJ);
        }
        for (int k = 0; k <= 32; ++k) {
            W[WOFF_SL + (tid * 33 + k) * 2]     = SLs[tid][k].x;
            W[WOFF_SL + (tid * 33 + k) * 2 + 1] = SLs[tid][k].y;
        }
    }
    __syncthreads();
    {
        // mtab: 64 rows x 128 bins; entry = #{k in 1..32 : S_k < u/128}
        const int e0  = tid * 16;           // 16 entries/thread, same row
        const int row = e0 >> 7;
        unsigned int packs[4] = {0, 0, 0, 0};
#pragma unroll
        for (int j = 0; j < 16; ++j) {
            const int   u  = (e0 + j) & 127;
            const float tu = __fmul_rn((float)u, 0.0078125f);   // exact
            int lo = 0;
#pragma unroll
            for (int s = 32; s >= 1; s >>= 1) {
                const int cand = lo + s;
                if (cand <= 32 && SLs[row][cand].x < tu) lo = cand;
            }
            packs[j >> 2] |= ((unsigned)lo) << ((j & 3) * 8);
        }
        unsigned int* Wm = reinterpret_cast<unsigned int*>(W + WOFF_MT);
#pragma unroll
        for (int j = 0; j < 4; ++j) Wm[tid * 4 + j] = packs[j];
    }
}

// ---------------------------------------------------------------------------
// Main kernel: coop-load 26 KB of tables, then the per-point path.
// Step-0 is the R9-VALIDATED exact form (IEEE divide r, v_log(max(r,EPS))
// * fl64(ln2/a)) — R12's log-difference variant is reverted (cancellation
// amplified by ln2/a poisoned lj, ERRATA of R12). Crossing count via mtab
// lower bound + exact fixup on the defining predicate (t0 > S_{m+1}).
// Chain fsub/fadd and terminal math byte-exact; v_exp last (no feedback).
// ---------------------------------------------------------------------------
__global__ __launch_bounds__(TPB) void cpab_main(const float* __restrict__ x_in,
                                                 const float* __restrict__ W,
                                                 float* __restrict__ out, int n) {
    __shared__ __align__(16) float LW[WTOT];
    const int   tid = threadIdx.x;
    const float INF = __builtin_inff();

    // prefetch x under the table load
    const int ti   = blockIdx.x * TPB + tid;
    const int base = ti << 2;
    float4 xv = make_float4(0.0f, 0.0f, 0.0f, 0.0f);
    const bool inb = (base + 3 < n);
    if (inb) xv = *reinterpret_cast<const float4*>(x_in + base);

    {
        const float4* Wv = reinterpret_cast<const float4*>(W);
        float4*       Lv = reinterpret_cast<float4*>(LW);
        for (int i = tid; i < WTOT / 4; i += TPB) Lv[i] = Wv[i];
    }
    __syncthreads();

    const float2* cAB = reinterpret_cast<const float2*>(LW + WOFF_CAB);
    const float2* tA  = reinterpret_cast<const float2*>(LW + WOFF_TA);
    const float4* aF  = reinterpret_cast<const float4*>(LW + WOFF_AF);
    const float2* SL  = reinterpret_cast<const float2*>(LW + WOFF_SL);
    const unsigned char* mt = reinterpret_cast<const unsigned char*>(LW + WOFF_MT);

    if (base >= n) return;
    float4 zo, jo;

#pragma unroll
    for (int q = 0; q < 4; ++q) {
        const float x0 = (q == 0) ? xv.x : (q == 1) ? xv.y : (q == 2) ? xv.z : xv.w;
        int c0 = (int)floorf(__fmul_rn(x0, 32.0f));
        c0 = min(max(c0, 0), NCC - 1);

        // ---- step 0 from arbitrary x0 (R9-exact arithmetic) ----
        const float2 ab   = cAB[c0];
        const float  v    = __fadd_rn(__fmul_rn(ab.x, x0), ab.y);
        const bool   dirA = v > 0.0f;
        const bool   fin  = dirA ? (c0 < NCC - 1) : (c0 > 0);
        const bool   v0   = (v == 0.0f);
        const bool   big  = fabsf(ab.x) > EPSF;
        const float2 ta   = tA[(dirA ? 32 : 0) + c0];   // {vc_target, ln2/a_s}
        const float  vc   = fin ? ta.x : v;
        const float  r    = vc / (v0 ? 1.0f : v);       // IEEE divide
        const float  th_a = __builtin_amdgcn_logf(fmaxf(r, EPSF)) * ta.y;
        float th_b = 0.0f;
        if (__any(!big)) {   // dead for gaussian A; exact when taken
            const float xcs = fin ? __fmul_rn((float)(c0 + (dirA ? 1 : 0)), 0.03125f) : x0;
            const float bb  = (fabsf(ab.y) > EPSF) ? ab.y : 1.0f;
            th_b = __fsub_rn(xcs, x0) / bb;
        }
        float th = big ? ((r > EPSF) ? th_a : INF) : th_b;
        const bool valid = fin && !v0 && (th > 0.0f);
        th = valid ? th : INF;

        const bool  cross0 = th < 1.0f;
        const float t0v    = __fsub_rn(1.0f, th);
        const float lj0    = __fmul_rn(ab.x, th);
        const int   dh     = dirA ? 1 : -1;
        const int   c1     = c0 + dh;
        const int   c1c    = min(max(c1, 0), NCC - 1);
        const int   row    = (dirA ? 32 : 0) + c1c;

        // ---- crossing count: mtab lower bound + exact fixup ----
        int u = (int)__fmul_rn(fmaxf(t0v, 0.0f), 128.0f);
        u = min(u, 127);
        int m = (int)mt[(row << 7) + u];
        while (m < 32 && t0v > SL[row * 33 + m + 1].x) ++m;
        const float2 slm = SL[row * 33 + m];

        const float tt = cross0 ? __fsub_rn(t0v, slm.x) : 1.0f;
        const float lj = cross0 ? __fadd_rn(lj0, slm.y) : 0.0f;
        int cf = cross0 ? (c1 + m * dh) : c0;
        cf = min(max(cf, 0), NCC - 1);
        const float xs = cross0 ? __fmul_rn((float)(cf + (dirA ? 0 : 1)), 0.03125f)
                                : x0;

        // ---- terminal: dt = tt; v_exp last (no feedback) ----
        const float4 af   = aF[cf];                     // {a, boa, b, 0}
        const bool   bigf = fabsf(af.x) > EPSF;
        const float  ad   = __fmul_rn(af.x, tt);
        const float  ea   = __builtin_amdgcn_exp2f(__fmul_rn(ad, 1.44269504088896340736f));
        const float  psi  = bigf ? __fsub_rn(__fmul_rn(ea, __fadd_rn(xs, af.y)), af.y)
                                 : __fadd_rn(xs, __fmul_rn(af.z, tt));
        const float  ljo  = __fadd_rn(lj, ad);
        if (q == 0) { zo.x = psi; jo.x = ljo; }
        if (q == 1) { zo.y = psi; jo.y = ljo; }
        if (q == 2) { zo.z = psi; jo.z = ljo; }
        if (q == 3) { zo.w = psi; jo.w = ljo; }
    }

    if (inb) {
        *reinterpret_cast<float4*>(out + base)     = zo;
        *reinterpret_cast<float4*>(out + n + base) = jo;
    } else {
        if (base < n)     { out[base]     = zo.x; out[n + base]     = jo.x; }
        if (base + 1 < n) { out[base + 1] = zo.y; out[n + base + 1] = jo.y; }
        if (base + 2 < n) { out[base + 2] = zo.z; out[n + base + 2] = jo.z; }
    }
}

extern "C" void kernel_launch(void* const* d_in, const int* in_sizes, int n_in,
                              void* d_out, int out_size, void* d_ws, size_t ws_size,
                              hipStream_t stream) {
    (void)ws_size; (void)n_in; (void)out_size;
    const float* x     = (const float*)d_in[0];
    const float* theta = (const float*)d_in[1];
    float*       out   = (float*)d_out;
    float*       W     = (float*)d_ws;
    const int    n     = in_sizes[0];

    cpab_setup<<<1, TPB, 0, stream>>>(theta, W);
    const int threads4 = (n + 3) >> 2;
    const int blocks   = (threads4 + TPB - 1) / TPB;
    cpab_main<<<blocks, TPB, 0, stream>>>(x, W, out, n);
}

// Round 14
// 18.059 us; speedup vs baseline: 1.3840x; 1.3840x over previous
//
#include <hip/hip_runtime.h>
#include <math.h>

#define NCC  32
#define EPSF 1e-10f
#define TPB  512

// ---------------------------------------------------------------------------
// Compile-time reproduction of numpy's SVD null-space basis (validated R1/R4):
// np.linalg.svd -> dgesdd (m=31<n=64, jobz='A') -> Path 4t: Vt[31:,:] ==
// Q[31:,:] of the Householder LQ (dgelqf) of L. A = B@theta = Q^T [0;theta].
// ---------------------------------------------------------------------------
struct MTab { float mt[33][64]; };

constexpr double csqrt_(double x) {
    double y = x > 1.0 ? x : 1.0;
    for (int i = 0; i < 80; ++i) y = 0.5 * (y + x / y);
    return y;
}

constexpr MTab make_mtab() {
    double Lm[31][64] = {};
    for (int k = 1; k < 32; ++k) {
        double xk = (double)k / 32.0;
        Lm[k - 1][2 * (k - 1)]     = xk;
        Lm[k - 1][2 * (k - 1) + 1] = 1.0;
        Lm[k - 1][2 * k]           = -xk;
        Lm[k - 1][2 * k + 1]       = -1.0;
    }
    double tau[31] = {};
    for (int i = 0; i < 31; ++i) {
        int E = 2 * i + 3; if (E > 63) E = 63;
        double xn2 = 0.0;
        for (int p = i + 1; p <= E; ++p) xn2 += Lm[i][p] * Lm[i][p];
        const double alpha = Lm[i][i];
        double tu = 0.0, sc = 0.0;
        if (xn2 != 0.0) {
            const double nrm  = csqrt_(alpha * alpha + xn2);
            const double beta = (alpha >= 0.0) ? -nrm : nrm;   // dlarfg sign
            tu = (beta - alpha) / beta;
            sc = 1.0 / (alpha - beta);
        }
        for (int p = i + 1; p <= E; ++p) Lm[i][p] *= sc;
        Lm[i][i] = 1.0;
        tau[i] = tu;
        for (int j = i + 1; j < 31; ++j) {
            double s = 0.0;
            for (int p = i; p <= E; ++p) s += Lm[i][p] * Lm[j][p];
            s *= tu;
            for (int p = i; p <= E; ++p) Lm[j][p] -= s * Lm[i][p];
        }
    }
    MTab o{};
    for (int col = 0; col < 33; ++col) {
        double u[64] = {};
        u[31 + col] = 1.0;
        for (int i = 30; i >= 0; --i) {
            int E = 2 * i + 3; if (E > 63) E = 63;
            double s = 0.0;
            for (int p = i; p <= E; ++p) s += Lm[i][p] * u[p];
            s *= tau[i];
            for (int p = i; p <= E; ++p) u[p] -= s * Lm[i][p];
        }
        for (int p = 0; p < 64; ++p) o.mt[col][p] = (float)u[p];
    }
    return o;
}

__constant__ const MTab dM = make_mtab();

// ---------------------------------------------------------------------------
// Invariants (validated R5-R13, bit-level): after a crossing, xs is the exact
// boundary float c'*2^-5; direction never flips; per-(cell,dir) t_hit and
// a*t_hit constants; cumsum S nondecreasing in f32 -> crossing count via
// binary search. Once-per-point bounded-error subs with no feedback
// (validated R9/R13): step-0 v_log(r_IEEE)*fl64(ln2/a); terminal v_exp.
// R12 ERRATA: log-difference form of th_a is FORBIDDEN (cancellation x ln2/a
// poisons lj). R14 = R9 base + float2-packed SL table (b64 probes) + merged
// preamble phases (same exprs, one fewer barrier). All value-producing
// arithmetic byte-identical to R9.
// ---------------------------------------------------------------------------
__global__ __launch_bounds__(TPB) void cpab_flow(const float* __restrict__ x_in,
                                                 const float* __restrict__ theta,
                                                 float* __restrict__ out, int n) {
    __shared__ float  sA[64];
    __shared__ float  aS[NCC], bS[NCC], boaS[NCC], vLS[NCC], vRS[NCC], laS[NCC];
    __shared__ float  thf[2][NCC], ljf[2][NCC];
    __shared__ float2 SL[64][33];   // {S_k, LJ_k} per (dir,start-cell) row

    const int   tid = threadIdx.x;
    const float INF = __builtin_inff();

    // ---- prefetch x: HBM latency resolves under the preamble ----
    const int ti   = blockIdx.x * TPB + tid;
    const int base = ti << 2;
    float4 xv = make_float4(0.0f, 0.0f, 0.0f, 0.0f);
    const bool inb = (base + 3 < n);
    if (inb) xv = *reinterpret_cast<const float4*>(x_in + base);

    if (tid < 64) {
        float acc = 0.0f;
#pragma unroll
        for (int j = 0; j < 33; ++j) acc = fmaf(dM.mt[j][tid], theta[j], acc);
        sA[tid] = acc;
    }
    __syncthreads();
    if (tid < 2 * NCC) {
        // merged phase: per-(dd,c) everything (thf needs only same-cell vals)
        const int   c   = tid & 31;
        const int   dd  = tid >> 5;
        const float a   = sA[2 * c];
        const float b   = sA[2 * c + 1];
        const bool  big = fabsf(a) > EPSF;
        const float vL  = __fadd_rn(__fmul_rn(a, __fmul_rn((float)c,       0.03125f)), b);
        const float vR  = __fadd_rn(__fmul_rn(a, __fmul_rn((float)(c + 1), 0.03125f)), b);
        if (dd == 0) {
            aS[c]   = a;
            bS[c]   = b;
            vLS[c]  = vL;
            vRS[c]  = vR;
            boaS[c] = b / (big ? a : 1.0f);                     // IEEE divide
            laS[c]  = (float)(0.6931471805599453094 / (double)(big ? a : 1.0f));
        }
        // thf[dd][c]: reference-exact t_hit (libm logf + IEEE divides)
        const float entry = __fmul_rn((float)(c + (dd ? 0 : 1)), 0.03125f);
        const float v     = dd ? vL : vR;
        const bool  dirA  = v > 0.0f;
        const bool  fin   = dirA ? (c < NCC - 1) : (c > 0);
        const float xb    = __fmul_rn((float)(c + (dirA ? 1 : 0)), 0.03125f);
        const float xcs   = fin ? xb : entry;
        const float vc    = fin ? (dirA ? vR : vL) : v;
        const bool  v0    = (v == 0.0f);
        const float r     = vc / (v0 ? 1.0f : v);               // IEEE divide
        const float a_s   = big ? a : 1.0f;
        const float th_a  = logf(fmaxf(r, EPSF)) / a_s;         // libm + divide
        const float bb    = (fabsf(b) > EPSF) ? b : 1.0f;
        const float th_b  = __fsub_rn(xcs, entry) / bb;
        float t_hit = big ? ((r > EPSF) ? th_a : INF) : th_b;
        const bool valid = fin && !v0 && (t_hit > 0.0f);
        t_hit = valid ? t_hit : INF;
        thf[dd][c] = t_hit;
        ljf[dd][c] = __fmul_rn(a, t_hit);
    }
    __syncthreads();
    if (tid < 2 * NCC) {
        // cumsum row (dd, c1): exact fadd chains; guards th=4 (> any t0 < 1)
        const int dd = tid >> 5, c1 = tid & 31, dh = dd ? 1 : -1;
        float S = 0.0f, LJ = 0.0f;
        SL[tid][0] = make_float2(0.0f, 0.0f);
#pragma unroll
        for (int k = 1; k <= 32; ++k) {
            const int cell = c1 + (k - 1) * dh;
            float th = 4.0f, lp = 0.0f;
            if (cell >= 0 && cell < NCC) {
                th = thf[dd][cell];
                lp = ljf[dd][cell];
                if (!(th <= 2.0f)) { th = 4.0f; lp = 0.0f; }
            }
            S  = __fadd_rn(S, th);
            LJ = __fadd_rn(LJ, lp);
            SL[tid][k] = make_float2(S, LJ);
        }
    }
    __syncthreads();

    if (base >= n) return;
    float4 zo, jo;

#pragma unroll
    for (int q = 0; q < 4; ++q) {
        const float x0 = (q == 0) ? xv.x : (q == 1) ? xv.y : (q == 2) ? xv.z : xv.w;
        int c0 = (int)floorf(__fmul_rn(x0, 32.0f));
        c0 = min(max(c0, 0), NCC - 1);

        // ---- step 0 from arbitrary x0 (R9-exact arithmetic) ----
        const float a    = aS[c0];
        const float b    = bS[c0];
        const float v    = __fadd_rn(__fmul_rn(a, x0), b);
        const bool  dirA = v > 0.0f;
        const bool  fin  = dirA ? (c0 < NCC - 1) : (c0 > 0);
        const float vc   = fin ? (dirA ? vRS[c0] : vLS[c0]) : v;
        const bool  v0   = (v == 0.0f);
        const float r    = vc / (v0 ? 1.0f : v);                // IEEE divide
        const bool  big  = fabsf(a) > EPSF;
        const float th_a = __builtin_amdgcn_logf(fmaxf(r, EPSF)) * laS[c0];
        float th_b = 0.0f;
        if (__any(!big)) {   // dead for gaussian A; exact when taken
            const float xcs = fin ? __fmul_rn((float)(c0 + (dirA ? 1 : 0)), 0.03125f) : x0;
            const float bb  = (fabsf(b) > EPSF) ? b : 1.0f;
            th_b = __fsub_rn(xcs, x0) / bb;
        }
        float th = big ? ((r > EPSF) ? th_a : INF) : th_b;
        const bool valid = fin && !v0 && (th > 0.0f);
        th = valid ? th : INF;

        const bool  cross0 = th < 1.0f;
        const float t0v    = __fsub_rn(1.0f, th);
        const float lj0    = __fmul_rn(a, th);
        const int   dh     = dirA ? 1 : -1;
        const int   c1     = c0 + dh;
        const int   c1c    = min(max(c1, 0), NCC - 1);
        const int   row    = (dirA ? NCC : 0) + c1c;

        // ---- crossing count: binary search, b64 probes on packed SL ----
        const float2* Srow = SL[row];
        int m = 0;
#pragma unroll
        for (int s = 32; s >= 1; s >>= 1) {
            const int cand  = m + s;
            const int candc = min(cand, 32);
            m = ((cand <= 32) && (t0v > Srow[candc].x)) ? cand : m;
        }
        const float2 slm = Srow[m];

        const float tt = cross0 ? __fsub_rn(t0v, slm.x) : 1.0f;
        const float lj = cross0 ? __fadd_rn(lj0, slm.y) : 0.0f;
        int cf = cross0 ? (c1 + m * dh) : c0;
        cf = min(max(cf, 0), NCC - 1);
        const float xs = cross0 ? __fmul_rn((float)(cf + (dirA ? 0 : 1)), 0.03125f)
                                : x0;

        // ---- terminal: dt = tt; v_exp last (no feedback) ----
        const float af   = aS[cf];
        const float bf   = bS[cf];
        const bool  bigf = fabsf(af) > EPSF;
        const float boa  = boaS[cf];
        const float ad   = __fmul_rn(af, tt);
        const float ea   = __builtin_amdgcn_exp2f(__fmul_rn(ad, 1.44269504088896340736f));
        const float psi  = bigf ? __fsub_rn(__fmul_rn(ea, __fadd_rn(xs, boa)), boa)
                                : __fadd_rn(xs, __fmul_rn(bf, tt));
        const float ljo  = __fadd_rn(lj, ad);
        if (q == 0) { zo.x = psi; jo.x = ljo; }
        if (q == 1) { zo.y = psi; jo.y = ljo; }
        if (q == 2) { zo.z = psi; jo.z = ljo; }
        if (q == 3) { zo.w = psi; jo.w = ljo; }
    }

    if (inb) {
        *reinterpret_cast<float4*>(out + base)     = zo;
        *reinterpret_cast<float4*>(out + n + base) = jo;
    } else {
        if (base < n)     { out[base]     = zo.x; out[n + base]     = jo.x; }
        if (base + 1 < n) { out[base + 1] = zo.y; out[n + base + 1] = jo.y; }
        if (base + 2 < n) { out[base + 2] = zo.z; out[n + base + 2] = jo.z; }
    }
}

extern "C" void kernel_launch(void* const* d_in, const int* in_sizes, int n_in,
                              void* d_out, int out_size, void* d_ws, size_t ws_size,
                              hipStream_t stream) {
    (void)d_ws; (void)ws_size; (void)n_in; (void)out_size;
    const float* x     = (const float*)d_in[0];
    const float* theta = (const float*)d_in[1];
    float*       out   = (float*)d_out;
    const int    n     = in_sizes[0];

    const int threads4 = (n + 3) >> 2;
    const int blocks   = (threads4 + TPB - 1) / TPB;
    cpab_flow<<<blocks, TPB, 0, stream>>>(x, theta, out, n);
}